// Round 11
// baseline (715.647 us; speedup 1.0000x reference)
//
#include <hip/hip_runtime.h>
#include <stdint.h>

typedef __attribute__((ext_vector_type(8))) short bf16x8;
typedef __attribute__((ext_vector_type(4))) float f32x4;

#define DEV __device__ __forceinline__

static constexpr int Bsz = 4, Lsz = 2048, Esz = 1024, Hsz = 16, HDsz = 64;
static constexpr int BL = Bsz * Lsz;              // 8192 rows
static constexpr size_t PLANE = (size_t)BL * Esz; // 8,388,608 elements

DEV unsigned short f2bf(float x) {
  union { float f; unsigned u; } c; c.f = x;
  unsigned u = c.u + 0x7FFFu + ((c.u >> 16) & 1u);
  return (unsigned short)(u >> 16);
}
DEV float bf2f(unsigned short h) {
  union { unsigned u; float f; } c; c.u = ((unsigned)h) << 16; return c.f;
}
DEV bf16x8 ld_bf8(const unsigned short* p) { return *(const bf16x8*)p; }

// ---------------------------------------------------------------------------
// NT GEMM with bias (VERBATIM from passing round-1/5/6/10 kernel).
// ---------------------------------------------------------------------------
template<bool A_F32, bool WRITE_LO, bool OUT_F32>
__global__ __launch_bounds__(256) void gemm_nt(
    const void* __restrict__ Aptr, const float* __restrict__ W,
    const float* __restrict__ bias, void* __restrict__ Cptr,
    unsigned short* __restrict__ Clo)
{
  constexpr int Kdim = Esz, Ndim = Esz;
  __shared__ unsigned short As[2][128][40];
  __shared__ unsigned short Bs[2][128][40];

  const int t = threadIdx.x;
  const int lane = t & 63, wave = t >> 6;
  const int wr = wave >> 1, wc = wave & 1;
  const int frow = lane & 15, fg = lane >> 4;

  const int f = blockIdx.x + 8 * blockIdx.y;          // [0,512)
  const int m_t = ((f & 7) << 3) + (f >> 6);          // 0..63
  const int n_t = (f >> 3) & 7;                       // 0..7
  const int m0 = m_t * 128, n0 = n_t * 128;

  f32x4 acc[4][4];
#pragma unroll
  for (int i = 0; i < 4; i++)
#pragma unroll
    for (int j = 0; j < 4; j++) acc[i][j] = f32x4{0.f, 0.f, 0.f, 0.f};

  for (int k0 = 0; k0 < Kdim; k0 += 32) {
    __syncthreads();
#pragma unroll
    for (int j = 0; j < 4; j++) {
      int s = t + j * 256, row = s >> 3, c4 = s & 7;
      if constexpr (A_F32) {
        const float* A = (const float*)Aptr;
        float4 v = *(const float4*)&A[(size_t)(m0 + row) * Kdim + k0 + c4 * 4];
        ushort4 hi, lo;
        hi.x = f2bf(v.x); lo.x = f2bf(v.x - bf2f(hi.x));
        hi.y = f2bf(v.y); lo.y = f2bf(v.y - bf2f(hi.y));
        hi.z = f2bf(v.z); lo.z = f2bf(v.z - bf2f(hi.z));
        hi.w = f2bf(v.w); lo.w = f2bf(v.w - bf2f(hi.w));
        *(ushort4*)&As[0][row][c4 * 4] = hi;
        *(ushort4*)&As[1][row][c4 * 4] = lo;
      } else {
        const unsigned short* A = (const unsigned short*)Aptr;
        ushort4 v = *(const ushort4*)&A[(size_t)(m0 + row) * Kdim + k0 + c4 * 4];
        *(ushort4*)&As[0][row][c4 * 4] = v;
      }
      {
        float4 v = *(const float4*)&W[(size_t)(n0 + row) * Kdim + k0 + c4 * 4];
        ushort4 hi, lo;
        hi.x = f2bf(v.x); lo.x = f2bf(v.x - bf2f(hi.x));
        hi.y = f2bf(v.y); lo.y = f2bf(v.y - bf2f(hi.y));
        hi.z = f2bf(v.z); lo.z = f2bf(v.z - bf2f(hi.z));
        hi.w = f2bf(v.w); lo.w = f2bf(v.w - bf2f(hi.w));
        *(ushort4*)&Bs[0][row][c4 * 4] = hi;
        *(ushort4*)&Bs[1][row][c4 * 4] = lo;
      }
    }
    __syncthreads();

    bf16x8 ah[4], al[4], bhv[4], blv[4];
#pragma unroll
    for (int x = 0; x < 4; x++) {
      ah[x] = ld_bf8(&As[0][wr * 64 + x * 16 + frow][fg * 8]);
      if constexpr (A_F32) al[x] = ld_bf8(&As[1][wr * 64 + x * 16 + frow][fg * 8]);
      bhv[x] = ld_bf8(&Bs[0][wc * 64 + x * 16 + frow][fg * 8]);
      blv[x] = ld_bf8(&Bs[1][wc * 64 + x * 16 + frow][fg * 8]);
    }
#pragma unroll
    for (int mi = 0; mi < 4; mi++)
#pragma unroll
      for (int ni = 0; ni < 4; ni++) {
        acc[mi][ni] = __builtin_amdgcn_mfma_f32_16x16x32_bf16(ah[mi], bhv[ni], acc[mi][ni], 0, 0, 0);
        acc[mi][ni] = __builtin_amdgcn_mfma_f32_16x16x32_bf16(ah[mi], blv[ni], acc[mi][ni], 0, 0, 0);
        if constexpr (A_F32)
          acc[mi][ni] = __builtin_amdgcn_mfma_f32_16x16x32_bf16(al[mi], bhv[ni], acc[mi][ni], 0, 0, 0);
      }
  }

  // C/D layout: col = lane&15, row = (lane>>4)*4 + reg
#pragma unroll
  for (int mi = 0; mi < 4; mi++)
#pragma unroll
    for (int ni = 0; ni < 4; ni++) {
      int col = n0 + wc * 64 + ni * 16 + frow;
      float bv = bias[col];
#pragma unroll
      for (int r = 0; r < 4; r++) {
        int row = m0 + wr * 64 + mi * 16 + fg * 4 + r;
        float val = acc[mi][ni][r] + bv;
        size_t idx = (size_t)row * Ndim + col;
        if constexpr (OUT_F32) {
          ((float*)Cptr)[idx] = val;
        } else {
          unsigned short hv = f2bf(val);
          ((unsigned short*)Cptr)[idx] = hv;
          if constexpr (WRITE_LO) Clo[idx] = f2bf(val - bf2f(hv));
        }
      }
    }
}

// ---------------------------------------------------------------------------
// Fused attention — R10 structure + two LDS changes:
//  * Ps aliased into the Q buffer (QP): Qh is dead after setup frag reads,
//    separated from first Ps write by all of pass A's barriers.
//  * Kl is always a full buffer; pass A double-buffers across Kh/Kl
//    (1 barrier/tile; write-next overlaps compute-current; T14 loads kept).
// LDS 46080 -> 36864 B. Pass B keeps R10's exact 3-barrier skeleton.
// Arithmetic orders identical to R6/R10.
// ---------------------------------------------------------------------------
template<bool SPLIT>
__global__ __launch_bounds__(256) void attn_fused(
    const unsigned short* __restrict__ qph, const unsigned short* __restrict__ qpl,
    const unsigned short* __restrict__ kph, const unsigned short* __restrict__ kpl,
    const unsigned short* __restrict__ vp,
    float* __restrict__ attn, unsigned short* __restrict__ oh)
{
  __shared__ unsigned short QP[64][72];      // Q-hi at setup; Ps in pass B
  __shared__ unsigned short Kh[64][72];
  __shared__ unsigned short Kl[64][72];      // Q-lo setup / pass-A dbuf / K-lo
  __shared__ unsigned short Vt[64][72];      // transposed: [d][k]

  const int t = threadIdx.x, lane = t & 63, wave = t >> 6;
  const int frow = lane & 15, fg = lane >> 4;

  const int f = blockIdx.x + 32 * blockIdx.y;       // [0,2048)
  const int bh = ((f & 7) << 3) + (f >> 8);         // 0..63
  const int qt = (f >> 3) & 31;                     // 0..31
  const int b = bh >> 4, h = bh & 15;
  const int q0 = qt * 64;
  const int qw = q0 + wave * 16;

  const size_t base = (size_t)b * Lsz * Esz + (size_t)h * HDsz;

  // per-thread staging coordinates (proven stage64 pattern)
  const int srow = t >> 4, sc4 = (t & 15) * 4;
  const int vrow = t >> 4, vc = t & 15;

  auto loadKh = [&](ushort4* r, int row0) {
#pragma unroll
    for (int j = 0; j < 4; j++)
      r[j] = *(const ushort4*)&kph[base + (size_t)(row0 + srow + j * 16) * Esz + sc4];
  };
  auto loadKl = [&](ushort4* r, int row0) {
#pragma unroll
    for (int j = 0; j < 4; j++)
      r[j] = *(const ushort4*)&kpl[base + (size_t)(row0 + srow + j * 16) * Esz + sc4];
  };
  auto writeK = [&](unsigned short (*dst)[72], const ushort4* r) {
#pragma unroll
    for (int j = 0; j < 4; j++)
      *(ushort4*)&dst[srow + j * 16][sc4] = r[j];
  };
  auto loadV = [&](unsigned short (*rv)[4], int row0) {
#pragma unroll
    for (int j = 0; j < 4; j++) {
      size_t g = base + (size_t)(row0 + vrow + j * 16) * Esz + vc;
#pragma unroll
      for (int i = 0; i < 4; i++) rv[j][i] = vp[g + i * 16];
    }
  };
  auto writeV = [&](unsigned short (*rv)[4]) {
#pragma unroll
    for (int j = 0; j < 4; j++) {
#pragma unroll
      for (int i = 0; i < 4; i++) Vt[vc + i * 16][vrow + j * 16] = rv[j][i];
    }
  };

  // ---- stage Q (hi -> QP, lo -> Kl) ----
#pragma unroll
  for (int j = 0; j < 4; j++) {
    size_t g = base + (size_t)(q0 + srow + j * 16) * Esz + sc4;
    *(ushort4*)&QP[srow + j * 16][sc4] = *(const ushort4*)&qph[g];
    if constexpr (SPLIT)
      *(ushort4*)&Kl[srow + j * 16][sc4] = *(const ushort4*)&qpl[g];
  }
  __syncthreads();
  bf16x8 qfh[2], qfl[2];
#pragma unroll
  for (int dh = 0; dh < 2; dh++) {
    qfh[dh] = ld_bf8(&QP[wave * 16 + frow][dh * 32 + fg * 8]);
    if constexpr (SPLIT) qfl[dh] = ld_bf8(&Kl[wave * 16 + frow][dh * 32 + fg * 8]);
  }

  float zl[4];
#pragma unroll
  for (int r = 0; r < 4; r++) zl[r] = 0.f;

  auto computeA = [&](unsigned short (*Kc)[72]) {
#pragma unroll
    for (int kc = 0; kc < 4; kc++) {
      f32x4 sv = f32x4{0.f, 0.f, 0.f, 0.f};
#pragma unroll
      for (int dh = 0; dh < 2; dh++) {
        bf16x8 kf = ld_bf8(&Kc[kc * 16 + frow][dh * 32 + fg * 8]);
        sv = __builtin_amdgcn_mfma_f32_16x16x32_bf16(qfh[dh], kf, sv, 0, 0, 0);
      }
#pragma unroll
      for (int r = 0; r < 4; r++) zl[r] += __expf(sv[r] * 0.125f);
    }
  };

  // ---- pass A: Z only; Kh/Kl double-buffer, 1 barrier/tile, T14 loads ----
  {
    ushort4 rA[4];
    loadKh(rA, 0);
    __syncthreads();                 // qf reads done (Kl held Q-lo)
    writeK(Kh, rA);                  // tile 0 -> Kh
    loadKh(rA, 64);                  // tile 1 -> regs
    __syncthreads();                 // tile 0 visible
    for (int kt = 0; kt < 32; kt++) {
      unsigned short (*cur)[72] = (kt & 1) ? Kl : Kh;
      unsigned short (*oth)[72] = (kt & 1) ? Kh : Kl;
      if (kt < 31) {
        writeK(oth, rA);             // tile kt+1 (oth was last read at kt-1)
        if (kt + 2 < 32) loadKh(rA, (kt + 2) * 64);
      }
      computeA(cur);
      __syncthreads();               // write(kt+1) visible; compute(kt) done
    }
  }
  float rz[4];
#pragma unroll
  for (int r = 0; r < 4; r++) {
    float z = zl[r];
#pragma unroll
    for (int o = 1; o < 16; o <<= 1) z += __shfl_xor(z, o);
    rz[r] = 1.f / z;
  }

  f32x4 oacc[4];
#pragma unroll
  for (int d = 0; d < 4; d++) oacc[d] = f32x4{0.f, 0.f, 0.f, 0.f};

  const size_t arow = (size_t)bh * Lsz * Lsz;

  auto computeB = [&](int kt) {
    f32x4 sv[4];
#pragma unroll
    for (int kc = 0; kc < 4; kc++) {
      sv[kc] = f32x4{0.f, 0.f, 0.f, 0.f};
#pragma unroll
      for (int dh = 0; dh < 2; dh++) {
        bf16x8 kfh = ld_bf8(&Kh[kc * 16 + frow][dh * 32 + fg * 8]);
        sv[kc] = __builtin_amdgcn_mfma_f32_16x16x32_bf16(qfh[dh], kfh, sv[kc], 0, 0, 0);
        if constexpr (SPLIT) {
          bf16x8 kfl = ld_bf8(&Kl[kc * 16 + frow][dh * 32 + fg * 8]);
          sv[kc] = __builtin_amdgcn_mfma_f32_16x16x32_bf16(qfh[dh], kfl, sv[kc], 0, 0, 0);
          sv[kc] = __builtin_amdgcn_mfma_f32_16x16x32_bf16(qfl[dh], kfh, sv[kc], 0, 0, 0);
        }
      }
    }
#pragma unroll
    for (int kc = 0; kc < 4; kc++) {
#pragma unroll
      for (int r = 0; r < 4; r++) {
        float p = __expf(sv[kc][r] * 0.125f) * rz[r];
        int qrow = qw + fg * 4 + r;
        attn[arow + (size_t)qrow * Lsz + kt * 64 + kc * 16 + frow] = p;
        QP[wave * 16 + fg * 4 + r][kc * 16 + frow] = f2bf(p);
      }
    }
    __syncthreads();  // Ps visibility (proven skeleton)
#pragma unroll
    for (int kh2 = 0; kh2 < 2; kh2++) {
      bf16x8 pa = ld_bf8(&QP[wave * 16 + frow][kh2 * 32 + fg * 8]);
#pragma unroll
      for (int d = 0; d < 4; d++) {
        bf16x8 vb = ld_bf8(&Vt[d * 16 + frow][kh2 * 32 + fg * 8]);
        oacc[d] = __builtin_amdgcn_mfma_f32_16x16x32_bf16(pa, vb, oacc[d], 0, 0, 0);
      }
    }
  };

  // ---- pass B: pipelined K(hi/lo)+V staging (R10 skeleton, 2x unroll) ----
  {
    ushort4 khA[4], khB[4], klA[4], klB[4];
    unsigned short vA[4][4], vB[4][4];
    loadKh(khA, 0);
    if constexpr (SPLIT) loadKl(klA, 0);
    loadV(vA, 0);
    for (int kt = 0; kt < 32; kt += 2) {
      __syncthreads();                 // prev PV done reading Vt; scores done Kh/Kl
      writeK(Kh, khA);
      if constexpr (SPLIT) writeK(Kl, klA);
      writeV(vA);
      if (kt + 1 < 32) {
        loadKh(khB, (kt + 1) * 64);
        if constexpr (SPLIT) loadKl(klB, (kt + 1) * 64);
        loadV(vB, (kt + 1) * 64);
      }
      __syncthreads();
      computeB(kt);
      __syncthreads();
      writeK(Kh, khB);
      if constexpr (SPLIT) writeK(Kl, klB);
      writeV(vB);
      if (kt + 2 < 32) {
        loadKh(khA, (kt + 2) * 64);
        if constexpr (SPLIT) loadKl(klA, (kt + 2) * 64);
        loadV(vA, (kt + 2) * 64);
      }
      __syncthreads();
      computeB(kt + 1);
    }
  }

  // write oh (bf16, [B,L,H,HD] head-interleaved)
#pragma unroll
  for (int d = 0; d < 4; d++)
#pragma unroll
    for (int r = 0; r < 4; r++) {
      int qrow = qw + fg * 4 + r;
      oh[base + (size_t)qrow * Esz + d * 16 + frow] = f2bf(oacc[d][r]);
    }
}

// ---------------------------------------------------------------------------
extern "C" void kernel_launch(void* const* d_in, const int* in_sizes, int n_in,
                              void* d_out, int out_size, void* d_ws, size_t ws_size,
                              hipStream_t stream)
{
  (void)in_sizes; (void)n_in; (void)out_size;

  const float* q  = (const float*)d_in[0];
  const float* k  = (const float*)d_in[1];
  const float* v  = (const float*)d_in[2];
  const float* Wq = (const float*)d_in[3];
  const float* bq = (const float*)d_in[4];
  const float* Wk = (const float*)d_in[5];
  const float* bk = (const float*)d_in[6];
  const float* Wv = (const float*)d_in[7];
  const float* bv = (const float*)d_in[8];
  const float* Wo = (const float*)d_in[9];
  const float* bo = (const float*)d_in[10];

  float* out  = (float*)d_out;
  float* attn = out + PLANE;  // output 1 follows output 0, flat

  unsigned short* qph = (unsigned short*)d_ws;
  unsigned short* kph = qph + PLANE;
  unsigned short* vpp = kph + PLANE;
  unsigned short* oh  = vpp + PLANE;
  unsigned short* qpl = oh  + PLANE;
  unsigned short* kpl = qpl + PLANE;
  const bool split = ws_size >= (size_t)6 * PLANE * sizeof(unsigned short);  // 96 MiB

  dim3 gg(8, 64), bb(256);
  if (split) {
    gemm_nt<true, true,  false><<<gg, bb, 0, stream>>>(q, Wq, bq, qph, qpl);
    gemm_nt<true, true,  false><<<gg, bb, 0, stream>>>(k, Wk, bk, kph, kpl);
  } else {
    gemm_nt<true, false, false><<<gg, bb, 0, stream>>>(q, Wq, bq, qph, nullptr);
    gemm_nt<true, false, false><<<gg, bb, 0, stream>>>(k, Wk, bk, kph, nullptr);
  }
  gemm_nt<true, false, false><<<gg, bb, 0, stream>>>(v, Wv, bv, vpp, nullptr);

  dim3 ga(32, 64);
  if (split)
    attn_fused<true ><<<ga, bb, 0, stream>>>(qph, qpl, kph, kpl, vpp, attn, oh);
  else
    attn_fused<false><<<ga, bb, 0, stream>>>(qph, nullptr, kph, nullptr, vpp, attn, oh);

  gemm_nt<false, false, true><<<gg, bb, 0, stream>>>(oh, Wo, bo, out, nullptr);
}

// Round 12
// 579.242 us; speedup vs baseline: 1.2355x; 1.2355x over previous
//
#include <hip/hip_runtime.h>
#include <stdint.h>

typedef __attribute__((ext_vector_type(8))) short bf16x8;
typedef __attribute__((ext_vector_type(4))) float f32x4;

#define DEV __device__ __forceinline__

static constexpr int Bsz = 4, Lsz = 2048, Esz = 1024, Hsz = 16, HDsz = 64;
static constexpr int BL = Bsz * Lsz;              // 8192 rows
static constexpr size_t PLANE = (size_t)BL * Esz; // 8,388,608 elements

DEV unsigned short f2bf(float x) {
  union { float f; unsigned u; } c; c.f = x;
  unsigned u = c.u + 0x7FFFu + ((c.u >> 16) & 1u);
  return (unsigned short)(u >> 16);
}
DEV float bf2f(unsigned short h) {
  union { unsigned u; float f; } c; c.u = ((unsigned)h) << 16; return c.f;
}
DEV bf16x8 ld_bf8(const unsigned short* p) { return *(const bf16x8*)p; }

// ---------------------------------------------------------------------------
// NT GEMM with bias (VERBATIM from passing round-1/5/6/10/11 kernel).
// ---------------------------------------------------------------------------
template<bool A_F32, bool WRITE_LO, bool OUT_F32>
__global__ __launch_bounds__(256) void gemm_nt(
    const void* __restrict__ Aptr, const float* __restrict__ W,
    const float* __restrict__ bias, void* __restrict__ Cptr,
    unsigned short* __restrict__ Clo)
{
  constexpr int Kdim = Esz, Ndim = Esz;
  __shared__ unsigned short As[2][128][40];
  __shared__ unsigned short Bs[2][128][40];

  const int t = threadIdx.x;
  const int lane = t & 63, wave = t >> 6;
  const int wr = wave >> 1, wc = wave & 1;
  const int frow = lane & 15, fg = lane >> 4;

  const int f = blockIdx.x + 8 * blockIdx.y;          // [0,512)
  const int m_t = ((f & 7) << 3) + (f >> 6);          // 0..63
  const int n_t = (f >> 3) & 7;                       // 0..7
  const int m0 = m_t * 128, n0 = n_t * 128;

  f32x4 acc[4][4];
#pragma unroll
  for (int i = 0; i < 4; i++)
#pragma unroll
    for (int j = 0; j < 4; j++) acc[i][j] = f32x4{0.f, 0.f, 0.f, 0.f};

  for (int k0 = 0; k0 < Kdim; k0 += 32) {
    __syncthreads();
#pragma unroll
    for (int j = 0; j < 4; j++) {
      int s = t + j * 256, row = s >> 3, c4 = s & 7;
      if constexpr (A_F32) {
        const float* A = (const float*)Aptr;
        float4 v = *(const float4*)&A[(size_t)(m0 + row) * Kdim + k0 + c4 * 4];
        ushort4 hi, lo;
        hi.x = f2bf(v.x); lo.x = f2bf(v.x - bf2f(hi.x));
        hi.y = f2bf(v.y); lo.y = f2bf(v.y - bf2f(hi.y));
        hi.z = f2bf(v.z); lo.z = f2bf(v.z - bf2f(hi.z));
        hi.w = f2bf(v.w); lo.w = f2bf(v.w - bf2f(hi.w));
        *(ushort4*)&As[0][row][c4 * 4] = hi;
        *(ushort4*)&As[1][row][c4 * 4] = lo;
      } else {
        const unsigned short* A = (const unsigned short*)Aptr;
        ushort4 v = *(const ushort4*)&A[(size_t)(m0 + row) * Kdim + k0 + c4 * 4];
        *(ushort4*)&As[0][row][c4 * 4] = v;
      }
      {
        float4 v = *(const float4*)&W[(size_t)(n0 + row) * Kdim + k0 + c4 * 4];
        ushort4 hi, lo;
        hi.x = f2bf(v.x); lo.x = f2bf(v.x - bf2f(hi.x));
        hi.y = f2bf(v.y); lo.y = f2bf(v.y - bf2f(hi.y));
        hi.z = f2bf(v.z); lo.z = f2bf(v.z - bf2f(hi.z));
        hi.w = f2bf(v.w); lo.w = f2bf(v.w - bf2f(hi.w));
        *(ushort4*)&Bs[0][row][c4 * 4] = hi;
        *(ushort4*)&Bs[1][row][c4 * 4] = lo;
      }
    }
    __syncthreads();

    bf16x8 ah[4], al[4], bhv[4], blv[4];
#pragma unroll
    for (int x = 0; x < 4; x++) {
      ah[x] = ld_bf8(&As[0][wr * 64 + x * 16 + frow][fg * 8]);
      if constexpr (A_F32) al[x] = ld_bf8(&As[1][wr * 64 + x * 16 + frow][fg * 8]);
      bhv[x] = ld_bf8(&Bs[0][wc * 64 + x * 16 + frow][fg * 8]);
      blv[x] = ld_bf8(&Bs[1][wc * 64 + x * 16 + frow][fg * 8]);
    }
#pragma unroll
    for (int mi = 0; mi < 4; mi++)
#pragma unroll
      for (int ni = 0; ni < 4; ni++) {
        acc[mi][ni] = __builtin_amdgcn_mfma_f32_16x16x32_bf16(ah[mi], bhv[ni], acc[mi][ni], 0, 0, 0);
        acc[mi][ni] = __builtin_amdgcn_mfma_f32_16x16x32_bf16(ah[mi], blv[ni], acc[mi][ni], 0, 0, 0);
        if constexpr (A_F32)
          acc[mi][ni] = __builtin_amdgcn_mfma_f32_16x16x32_bf16(al[mi], bhv[ni], acc[mi][ni], 0, 0, 0);
      }
  }

  // C/D layout: col = lane&15, row = (lane>>4)*4 + reg
#pragma unroll
  for (int mi = 0; mi < 4; mi++)
#pragma unroll
    for (int ni = 0; ni < 4; ni++) {
      int col = n0 + wc * 64 + ni * 16 + frow;
      float bv = bias[col];
#pragma unroll
      for (int r = 0; r < 4; r++) {
        int row = m0 + wr * 64 + mi * 16 + fg * 4 + r;
        float val = acc[mi][ni][r] + bv;
        size_t idx = (size_t)row * Ndim + col;
        if constexpr (OUT_F32) {
          ((float*)Cptr)[idx] = val;
        } else {
          unsigned short hv = f2bf(val);
          ((unsigned short*)Cptr)[idx] = hv;
          if constexpr (WRITE_LO) Clo[idx] = f2bf(val - bf2f(hv));
        }
      }
    }
}

// ---------------------------------------------------------------------------
// Fused attention — R11 structure, launched NON-SPLIT (hi-only scores):
// pass A (Z) and pass B (P) both use hi-plane scores => self-consistent
// softmax of bf16-rounded q/k; MFMA volume drops 172->103 GF.
// attn/oh written with nontemporal stores (never re-read; keeps K/V in L2).
// ---------------------------------------------------------------------------
template<bool SPLIT>
__global__ __launch_bounds__(256) void attn_fused(
    const unsigned short* __restrict__ qph, const unsigned short* __restrict__ qpl,
    const unsigned short* __restrict__ kph, const unsigned short* __restrict__ kpl,
    const unsigned short* __restrict__ vp,
    float* __restrict__ attn, unsigned short* __restrict__ oh)
{
  __shared__ unsigned short QP[64][72];      // Q-hi at setup; Ps in pass B
  __shared__ unsigned short Kh[64][72];
  __shared__ unsigned short Kl[64][72];      // Q-lo setup / pass-A dbuf / K-lo
  __shared__ unsigned short Vt[64][72];      // transposed: [d][k]

  const int t = threadIdx.x, lane = t & 63, wave = t >> 6;
  const int frow = lane & 15, fg = lane >> 4;

  const int f = blockIdx.x + 32 * blockIdx.y;       // [0,2048)
  const int bh = ((f & 7) << 3) + (f >> 8);         // 0..63
  const int qt = (f >> 3) & 31;                     // 0..31
  const int b = bh >> 4, h = bh & 15;
  const int q0 = qt * 64;
  const int qw = q0 + wave * 16;

  const size_t base = (size_t)b * Lsz * Esz + (size_t)h * HDsz;

  const int srow = t >> 4, sc4 = (t & 15) * 4;
  const int vrow = t >> 4, vc = t & 15;

  auto loadKh = [&](ushort4* r, int row0) {
#pragma unroll
    for (int j = 0; j < 4; j++)
      r[j] = *(const ushort4*)&kph[base + (size_t)(row0 + srow + j * 16) * Esz + sc4];
  };
  auto loadKl = [&](ushort4* r, int row0) {
#pragma unroll
    for (int j = 0; j < 4; j++)
      r[j] = *(const ushort4*)&kpl[base + (size_t)(row0 + srow + j * 16) * Esz + sc4];
  };
  auto writeK = [&](unsigned short (*dst)[72], const ushort4* r) {
#pragma unroll
    for (int j = 0; j < 4; j++)
      *(ushort4*)&dst[srow + j * 16][sc4] = r[j];
  };
  auto loadV = [&](unsigned short (*rv)[4], int row0) {
#pragma unroll
    for (int j = 0; j < 4; j++) {
      size_t g = base + (size_t)(row0 + vrow + j * 16) * Esz + vc;
#pragma unroll
      for (int i = 0; i < 4; i++) rv[j][i] = vp[g + i * 16];
    }
  };
  auto writeV = [&](unsigned short (*rv)[4]) {
#pragma unroll
    for (int j = 0; j < 4; j++) {
#pragma unroll
      for (int i = 0; i < 4; i++) Vt[vc + i * 16][vrow + j * 16] = rv[j][i];
    }
  };

  // ---- stage Q (hi -> QP, lo -> Kl) ----
#pragma unroll
  for (int j = 0; j < 4; j++) {
    size_t g = base + (size_t)(q0 + srow + j * 16) * Esz + sc4;
    *(ushort4*)&QP[srow + j * 16][sc4] = *(const ushort4*)&qph[g];
    if constexpr (SPLIT)
      *(ushort4*)&Kl[srow + j * 16][sc4] = *(const ushort4*)&qpl[g];
  }
  __syncthreads();
  bf16x8 qfh[2], qfl[2];
#pragma unroll
  for (int dh = 0; dh < 2; dh++) {
    qfh[dh] = ld_bf8(&QP[wave * 16 + frow][dh * 32 + fg * 8]);
    if constexpr (SPLIT) qfl[dh] = ld_bf8(&Kl[wave * 16 + frow][dh * 32 + fg * 8]);
  }

  float zl[4];
#pragma unroll
  for (int r = 0; r < 4; r++) zl[r] = 0.f;

  auto computeA = [&](unsigned short (*Kc)[72]) {
#pragma unroll
    for (int kc = 0; kc < 4; kc++) {
      f32x4 sv = f32x4{0.f, 0.f, 0.f, 0.f};
#pragma unroll
      for (int dh = 0; dh < 2; dh++) {
        bf16x8 kf = ld_bf8(&Kc[kc * 16 + frow][dh * 32 + fg * 8]);
        sv = __builtin_amdgcn_mfma_f32_16x16x32_bf16(qfh[dh], kf, sv, 0, 0, 0);
      }
#pragma unroll
      for (int r = 0; r < 4; r++) zl[r] += __expf(sv[r] * 0.125f);
    }
  };

  // ---- pass A: Z only; Kh/Kl double-buffer, 1 barrier/tile, T14 loads ----
  {
    ushort4 rA[4];
    loadKh(rA, 0);
    __syncthreads();                 // qf reads done (Kl held Q-lo)
    writeK(Kh, rA);                  // tile 0 -> Kh
    loadKh(rA, 64);                  // tile 1 -> regs
    __syncthreads();                 // tile 0 visible
    for (int kt = 0; kt < 32; kt++) {
      unsigned short (*cur)[72] = (kt & 1) ? Kl : Kh;
      unsigned short (*oth)[72] = (kt & 1) ? Kh : Kl;
      if (kt < 31) {
        writeK(oth, rA);             // tile kt+1 (oth was last read at kt-1)
        if (kt + 2 < 32) loadKh(rA, (kt + 2) * 64);
      }
      computeA(cur);
      __syncthreads();               // write(kt+1) visible; compute(kt) done
    }
  }
  float rz[4];
#pragma unroll
  for (int r = 0; r < 4; r++) {
    float z = zl[r];
#pragma unroll
    for (int o = 1; o < 16; o <<= 1) z += __shfl_xor(z, o);
    rz[r] = 1.f / z;
  }

  f32x4 oacc[4];
#pragma unroll
  for (int d = 0; d < 4; d++) oacc[d] = f32x4{0.f, 0.f, 0.f, 0.f};

  const size_t arow = (size_t)bh * Lsz * Lsz;

  auto computeB = [&](int kt) {
    f32x4 sv[4];
#pragma unroll
    for (int kc = 0; kc < 4; kc++) {
      sv[kc] = f32x4{0.f, 0.f, 0.f, 0.f};
#pragma unroll
      for (int dh = 0; dh < 2; dh++) {
        bf16x8 kfh = ld_bf8(&Kh[kc * 16 + frow][dh * 32 + fg * 8]);
        sv[kc] = __builtin_amdgcn_mfma_f32_16x16x32_bf16(qfh[dh], kfh, sv[kc], 0, 0, 0);
        if constexpr (SPLIT) {
          bf16x8 kfl = ld_bf8(&Kl[kc * 16 + frow][dh * 32 + fg * 8]);
          sv[kc] = __builtin_amdgcn_mfma_f32_16x16x32_bf16(qfh[dh], kfl, sv[kc], 0, 0, 0);
          sv[kc] = __builtin_amdgcn_mfma_f32_16x16x32_bf16(qfl[dh], kfh, sv[kc], 0, 0, 0);
        }
      }
    }
#pragma unroll
    for (int kc = 0; kc < 4; kc++) {
#pragma unroll
      for (int r = 0; r < 4; r++) {
        float p = __expf(sv[kc][r] * 0.125f) * rz[r];
        int qrow = qw + fg * 4 + r;
        __builtin_nontemporal_store(p, &attn[arow + (size_t)qrow * Lsz + kt * 64 + kc * 16 + frow]);
        QP[wave * 16 + fg * 4 + r][kc * 16 + frow] = f2bf(p);
      }
    }
    __syncthreads();  // Ps visibility (proven skeleton)
#pragma unroll
    for (int kh2 = 0; kh2 < 2; kh2++) {
      bf16x8 pa = ld_bf8(&QP[wave * 16 + frow][kh2 * 32 + fg * 8]);
#pragma unroll
      for (int d = 0; d < 4; d++) {
        bf16x8 vb = ld_bf8(&Vt[d * 16 + frow][kh2 * 32 + fg * 8]);
        oacc[d] = __builtin_amdgcn_mfma_f32_16x16x32_bf16(pa, vb, oacc[d], 0, 0, 0);
      }
    }
  };

  // ---- pass B: pipelined K+V staging (R10/R11 skeleton, 2x unroll) ----
  {
    ushort4 khA[4], khB[4], klA[4], klB[4];
    unsigned short vA[4][4], vB[4][4];
    loadKh(khA, 0);
    if constexpr (SPLIT) loadKl(klA, 0);
    loadV(vA, 0);
    for (int kt = 0; kt < 32; kt += 2) {
      __syncthreads();                 // prev PV done reading Vt; scores done Kh/Kl
      writeK(Kh, khA);
      if constexpr (SPLIT) writeK(Kl, klA);
      writeV(vA);
      if (kt + 1 < 32) {
        loadKh(khB, (kt + 1) * 64);
        if constexpr (SPLIT) loadKl(klB, (kt + 1) * 64);
        loadV(vB, (kt + 1) * 64);
      }
      __syncthreads();
      computeB(kt);
      __syncthreads();
      writeK(Kh, khB);
      if constexpr (SPLIT) writeK(Kl, klB);
      writeV(vB);
      if (kt + 2 < 32) {
        loadKh(khA, (kt + 2) * 64);
        if constexpr (SPLIT) loadKl(klA, (kt + 2) * 64);
        loadV(vA, (kt + 2) * 64);
      }
      __syncthreads();
      computeB(kt + 1);
    }
  }

  // write oh (bf16, [B,L,H,HD] head-interleaved), nontemporal
#pragma unroll
  for (int d = 0; d < 4; d++)
#pragma unroll
    for (int r = 0; r < 4; r++) {
      int qrow = qw + fg * 4 + r;
      __builtin_nontemporal_store(f2bf(oacc[d][r]),
          &oh[base + (size_t)qrow * Esz + d * 16 + frow]);
    }
}

// ---------------------------------------------------------------------------
extern "C" void kernel_launch(void* const* d_in, const int* in_sizes, int n_in,
                              void* d_out, int out_size, void* d_ws, size_t ws_size,
                              hipStream_t stream)
{
  (void)in_sizes; (void)n_in; (void)out_size; (void)ws_size;

  const float* q  = (const float*)d_in[0];
  const float* k  = (const float*)d_in[1];
  const float* v  = (const float*)d_in[2];
  const float* Wq = (const float*)d_in[3];
  const float* bq = (const float*)d_in[4];
  const float* Wk = (const float*)d_in[5];
  const float* bk = (const float*)d_in[6];
  const float* Wv = (const float*)d_in[7];
  const float* bv = (const float*)d_in[8];
  const float* Wo = (const float*)d_in[9];
  const float* bo = (const float*)d_in[10];

  float* out  = (float*)d_out;
  float* attn = out + PLANE;  // output 1 follows output 0, flat

  unsigned short* qph = (unsigned short*)d_ws;
  unsigned short* kph = qph + PLANE;
  unsigned short* vpp = kph + PLANE;
  unsigned short* oh  = vpp + PLANE;

  dim3 gg(8, 64), bb(256);
  // hi-only pipeline: projections computed in split-f32 precision internally,
  // outputs rounded to bf16 hi planes only.
  gemm_nt<true, false, false><<<gg, bb, 0, stream>>>(q, Wq, bq, qph, nullptr);
  gemm_nt<true, false, false><<<gg, bb, 0, stream>>>(k, Wk, bk, kph, nullptr);
  gemm_nt<true, false, false><<<gg, bb, 0, stream>>>(v, Wv, bv, vpp, nullptr);

  dim3 ga(32, 64);
  attn_fused<false><<<ga, bb, 0, stream>>>(qph, nullptr, kph, nullptr, vpp, attn, oh);

  gemm_nt<false, false, true><<<gg, bb, 0, stream>>>(oh, Wo, bo, out, nullptr);
}

// Round 13
// 553.986 us; speedup vs baseline: 1.2918x; 1.0456x over previous
//
#include <hip/hip_runtime.h>
#include <stdint.h>

typedef __attribute__((ext_vector_type(8))) short bf16x8;
typedef __attribute__((ext_vector_type(4))) float f32x4;

#define DEV __device__ __forceinline__

static constexpr int Bsz = 4, Lsz = 2048, Esz = 1024, Hsz = 16, HDsz = 64;
static constexpr int BL = Bsz * Lsz;              // 8192 rows
static constexpr size_t PLANE = (size_t)BL * Esz; // 8,388,608 elements

DEV unsigned short f2bf(float x) {
  union { float f; unsigned u; } c; c.f = x;
  unsigned u = c.u + 0x7FFFu + ((c.u >> 16) & 1u);
  return (unsigned short)(u >> 16);
}
DEV float bf2f(unsigned short h) {
  union { unsigned u; float f; } c; c.u = ((unsigned)h) << 16; return c.f;
}
DEV bf16x8 ld_bf8(const unsigned short* p) { return *(const bf16x8*)p; }

// ---------------------------------------------------------------------------
// NT GEMM with bias: C[M,N] = A[M,K] * W[N,K]^T + bias.
// W split hi/lo (2 MFMA: ah*bh + ah*bl). A rounded to bf16 (hi only) —
// justified: downstream consumers are self-consistent on bf16 planes and the
// dropped al*bh term (~1.2e-3 sigma) is below the bf16 output rounding.
// ---------------------------------------------------------------------------
template<bool A_F32, bool OUT_F32>
__global__ __launch_bounds__(256) void gemm_nt(
    const void* __restrict__ Aptr, const float* __restrict__ W,
    const float* __restrict__ bias, void* __restrict__ Cptr)
{
  constexpr int Kdim = Esz, Ndim = Esz;
  __shared__ unsigned short As[128][40];
  __shared__ unsigned short Bs[2][128][40];

  const int t = threadIdx.x;
  const int lane = t & 63, wave = t >> 6;
  const int wr = wave >> 1, wc = wave & 1;
  const int frow = lane & 15, fg = lane >> 4;

  const int f = blockIdx.x + 8 * blockIdx.y;          // [0,512)
  const int m_t = ((f & 7) << 3) + (f >> 6);          // 0..63
  const int n_t = (f >> 3) & 7;                       // 0..7
  const int m0 = m_t * 128, n0 = n_t * 128;

  f32x4 acc[4][4];
#pragma unroll
  for (int i = 0; i < 4; i++)
#pragma unroll
    for (int j = 0; j < 4; j++) acc[i][j] = f32x4{0.f, 0.f, 0.f, 0.f};

  for (int k0 = 0; k0 < Kdim; k0 += 32) {
    __syncthreads();
#pragma unroll
    for (int j = 0; j < 4; j++) {
      int s = t + j * 256, row = s >> 3, c4 = s & 7;
      if constexpr (A_F32) {
        const float* A = (const float*)Aptr;
        float4 v = *(const float4*)&A[(size_t)(m0 + row) * Kdim + k0 + c4 * 4];
        ushort4 hi;
        hi.x = f2bf(v.x); hi.y = f2bf(v.y); hi.z = f2bf(v.z); hi.w = f2bf(v.w);
        *(ushort4*)&As[row][c4 * 4] = hi;
      } else {
        const unsigned short* A = (const unsigned short*)Aptr;
        ushort4 v = *(const ushort4*)&A[(size_t)(m0 + row) * Kdim + k0 + c4 * 4];
        *(ushort4*)&As[row][c4 * 4] = v;
      }
      {
        float4 v = *(const float4*)&W[(size_t)(n0 + row) * Kdim + k0 + c4 * 4];
        ushort4 hi, lo;
        hi.x = f2bf(v.x); lo.x = f2bf(v.x - bf2f(hi.x));
        hi.y = f2bf(v.y); lo.y = f2bf(v.y - bf2f(hi.y));
        hi.z = f2bf(v.z); lo.z = f2bf(v.z - bf2f(hi.z));
        hi.w = f2bf(v.w); lo.w = f2bf(v.w - bf2f(hi.w));
        *(ushort4*)&Bs[0][row][c4 * 4] = hi;
        *(ushort4*)&Bs[1][row][c4 * 4] = lo;
      }
    }
    __syncthreads();

    bf16x8 ah[4], bhv[4], blv[4];
#pragma unroll
    for (int x = 0; x < 4; x++) {
      ah[x] = ld_bf8(&As[wr * 64 + x * 16 + frow][fg * 8]);
      bhv[x] = ld_bf8(&Bs[0][wc * 64 + x * 16 + frow][fg * 8]);
      blv[x] = ld_bf8(&Bs[1][wc * 64 + x * 16 + frow][fg * 8]);
    }
#pragma unroll
    for (int mi = 0; mi < 4; mi++)
#pragma unroll
      for (int ni = 0; ni < 4; ni++) {
        acc[mi][ni] = __builtin_amdgcn_mfma_f32_16x16x32_bf16(ah[mi], bhv[ni], acc[mi][ni], 0, 0, 0);
        acc[mi][ni] = __builtin_amdgcn_mfma_f32_16x16x32_bf16(ah[mi], blv[ni], acc[mi][ni], 0, 0, 0);
      }
  }

  // C/D layout: col = lane&15, row = (lane>>4)*4 + reg
#pragma unroll
  for (int mi = 0; mi < 4; mi++)
#pragma unroll
    for (int ni = 0; ni < 4; ni++) {
      int col = n0 + wc * 64 + ni * 16 + frow;
      float bv = bias[col];
#pragma unroll
      for (int r = 0; r < 4; r++) {
        int row = m0 + wr * 64 + mi * 16 + fg * 4 + r;
        float val = acc[mi][ni][r] + bv;
        size_t idx = (size_t)row * Ndim + col;
        if constexpr (OUT_F32) ((float*)Cptr)[idx] = val;
        else                   ((unsigned short*)Cptr)[idx] = f2bf(val);
      }
    }
}

// ---------------------------------------------------------------------------
// Fused attention — R12 structure verbatim, except exp via exp2f with the
// softmax scale folded into one constant (consistent in passes A and B, so
// Z and p remain mutually normalized).
// ---------------------------------------------------------------------------
__global__ __launch_bounds__(256) void attn_fused(
    const unsigned short* __restrict__ qph, const unsigned short* __restrict__ kph,
    const unsigned short* __restrict__ vp,
    float* __restrict__ attn, unsigned short* __restrict__ oh)
{
  __shared__ unsigned short QP[64][72];      // Q-hi at setup; Ps in pass B
  __shared__ unsigned short Kh[64][72];
  __shared__ unsigned short Kl[64][72];      // pass-A dbuf half
  __shared__ unsigned short Vt[64][72];      // transposed: [d][k]

  const int t = threadIdx.x, lane = t & 63, wave = t >> 6;
  const int frow = lane & 15, fg = lane >> 4;

  const int f = blockIdx.x + 32 * blockIdx.y;       // [0,2048)
  const int bh = ((f & 7) << 3) + (f >> 8);         // 0..63
  const int qt = (f >> 3) & 31;                     // 0..31
  const int b = bh >> 4, h = bh & 15;
  const int q0 = qt * 64;
  const int qw = q0 + wave * 16;

  const size_t base = (size_t)b * Lsz * Esz + (size_t)h * HDsz;
  constexpr float SC2 = 0.1803368801f;  // 0.125 * log2(e)

  const int srow = t >> 4, sc4 = (t & 15) * 4;
  const int vrow = t >> 4, vc = t & 15;

  auto loadKh = [&](ushort4* r, int row0) {
#pragma unroll
    for (int j = 0; j < 4; j++)
      r[j] = *(const ushort4*)&kph[base + (size_t)(row0 + srow + j * 16) * Esz + sc4];
  };
  auto writeK = [&](unsigned short (*dst)[72], const ushort4* r) {
#pragma unroll
    for (int j = 0; j < 4; j++)
      *(ushort4*)&dst[srow + j * 16][sc4] = r[j];
  };
  auto loadV = [&](unsigned short (*rv)[4], int row0) {
#pragma unroll
    for (int j = 0; j < 4; j++) {
      size_t g = base + (size_t)(row0 + vrow + j * 16) * Esz + vc;
#pragma unroll
      for (int i = 0; i < 4; i++) rv[j][i] = vp[g + i * 16];
    }
  };
  auto writeV = [&](unsigned short (*rv)[4]) {
#pragma unroll
    for (int j = 0; j < 4; j++) {
#pragma unroll
      for (int i = 0; i < 4; i++) Vt[vc + i * 16][vrow + j * 16] = rv[j][i];
    }
  };

  // ---- stage Q (hi -> QP) ----
#pragma unroll
  for (int j = 0; j < 4; j++) {
    size_t g = base + (size_t)(q0 + srow + j * 16) * Esz + sc4;
    *(ushort4*)&QP[srow + j * 16][sc4] = *(const ushort4*)&qph[g];
  }
  __syncthreads();
  bf16x8 qfh[2];
#pragma unroll
  for (int dh = 0; dh < 2; dh++)
    qfh[dh] = ld_bf8(&QP[wave * 16 + frow][dh * 32 + fg * 8]);

  float zl[4];
#pragma unroll
  for (int r = 0; r < 4; r++) zl[r] = 0.f;

  auto computeA = [&](unsigned short (*Kc)[72]) {
#pragma unroll
    for (int kc = 0; kc < 4; kc++) {
      f32x4 sv = f32x4{0.f, 0.f, 0.f, 0.f};
#pragma unroll
      for (int dh = 0; dh < 2; dh++) {
        bf16x8 kf = ld_bf8(&Kc[kc * 16 + frow][dh * 32 + fg * 8]);
        sv = __builtin_amdgcn_mfma_f32_16x16x32_bf16(qfh[dh], kf, sv, 0, 0, 0);
      }
#pragma unroll
      for (int r = 0; r < 4; r++) zl[r] += exp2f(sv[r] * SC2);
    }
  };

  // ---- pass A: Z only; Kh/Kl double-buffer, 1 barrier/tile, T14 loads ----
  {
    ushort4 rA[4];
    loadKh(rA, 0);
    __syncthreads();                 // qf reads done
    writeK(Kh, rA);                  // tile 0 -> Kh
    loadKh(rA, 64);                  // tile 1 -> regs
    __syncthreads();                 // tile 0 visible
    for (int kt = 0; kt < 32; kt++) {
      unsigned short (*cur)[72] = (kt & 1) ? Kl : Kh;
      unsigned short (*oth)[72] = (kt & 1) ? Kh : Kl;
      if (kt < 31) {
        writeK(oth, rA);             // tile kt+1 (oth was last read at kt-1)
        if (kt + 2 < 32) loadKh(rA, (kt + 2) * 64);
      }
      computeA(cur);
      __syncthreads();               // write(kt+1) visible; compute(kt) done
    }
  }
  float rz[4];
#pragma unroll
  for (int r = 0; r < 4; r++) {
    float z = zl[r];
#pragma unroll
    for (int o = 1; o < 16; o <<= 1) z += __shfl_xor(z, o);
    rz[r] = 1.f / z;
  }

  f32x4 oacc[4];
#pragma unroll
  for (int d = 0; d < 4; d++) oacc[d] = f32x4{0.f, 0.f, 0.f, 0.f};

  const size_t arow = (size_t)bh * Lsz * Lsz;

  auto computeB = [&](int kt) {
    f32x4 sv[4];
#pragma unroll
    for (int kc = 0; kc < 4; kc++) {
      sv[kc] = f32x4{0.f, 0.f, 0.f, 0.f};
#pragma unroll
      for (int dh = 0; dh < 2; dh++) {
        bf16x8 kfh = ld_bf8(&Kh[kc * 16 + frow][dh * 32 + fg * 8]);
        sv[kc] = __builtin_amdgcn_mfma_f32_16x16x32_bf16(qfh[dh], kfh, sv[kc], 0, 0, 0);
      }
    }
#pragma unroll
    for (int kc = 0; kc < 4; kc++) {
#pragma unroll
      for (int r = 0; r < 4; r++) {
        float p = exp2f(sv[kc][r] * SC2) * rz[r];
        int qrow = qw + fg * 4 + r;
        __builtin_nontemporal_store(p, &attn[arow + (size_t)qrow * Lsz + kt * 64 + kc * 16 + frow]);
        QP[wave * 16 + fg * 4 + r][kc * 16 + frow] = f2bf(p);
      }
    }
    __syncthreads();  // Ps visibility (proven skeleton)
#pragma unroll
    for (int kh2 = 0; kh2 < 2; kh2++) {
      bf16x8 pa = ld_bf8(&QP[wave * 16 + frow][kh2 * 32 + fg * 8]);
#pragma unroll
      for (int d = 0; d < 4; d++) {
        bf16x8 vb = ld_bf8(&Vt[d * 16 + frow][kh2 * 32 + fg * 8]);
        oacc[d] = __builtin_amdgcn_mfma_f32_16x16x32_bf16(pa, vb, oacc[d], 0, 0, 0);
      }
    }
  };

  // ---- pass B: pipelined K+V staging (R10/R11/R12 skeleton, 2x unroll) ----
  {
    ushort4 khA[4], khB[4];
    unsigned short vA[4][4], vB[4][4];
    loadKh(khA, 0);
    loadV(vA, 0);
    for (int kt = 0; kt < 32; kt += 2) {
      __syncthreads();                 // prev PV done reading Vt; scores done Kh
      writeK(Kh, khA);
      writeV(vA);
      if (kt + 1 < 32) {
        loadKh(khB, (kt + 1) * 64);
        loadV(vB, (kt + 1) * 64);
      }
      __syncthreads();
      computeB(kt);
      __syncthreads();
      writeK(Kh, khB);
      writeV(vB);
      if (kt + 2 < 32) {
        loadKh(khA, (kt + 2) * 64);
        loadV(vA, (kt + 2) * 64);
      }
      __syncthreads();
      computeB(kt + 1);
    }
  }

  // write oh (bf16, [B,L,H,HD] head-interleaved), nontemporal
#pragma unroll
  for (int d = 0; d < 4; d++)
#pragma unroll
    for (int r = 0; r < 4; r++) {
      int qrow = qw + fg * 4 + r;
      __builtin_nontemporal_store(f2bf(oacc[d][r]),
          &oh[base + (size_t)qrow * Esz + d * 16 + frow]);
    }
}

// ---------------------------------------------------------------------------
extern "C" void kernel_launch(void* const* d_in, const int* in_sizes, int n_in,
                              void* d_out, int out_size, void* d_ws, size_t ws_size,
                              hipStream_t stream)
{
  (void)in_sizes; (void)n_in; (void)out_size; (void)ws_size;

  const float* q  = (const float*)d_in[0];
  const float* k  = (const float*)d_in[1];
  const float* v  = (const float*)d_in[2];
  const float* Wq = (const float*)d_in[3];
  const float* bq = (const float*)d_in[4];
  const float* Wk = (const float*)d_in[5];
  const float* bk = (const float*)d_in[6];
  const float* Wv = (const float*)d_in[7];
  const float* bv = (const float*)d_in[8];
  const float* Wo = (const float*)d_in[9];
  const float* bo = (const float*)d_in[10];

  float* out  = (float*)d_out;
  float* attn = out + PLANE;  // output 1 follows output 0, flat

  unsigned short* qph = (unsigned short*)d_ws;
  unsigned short* kph = qph + PLANE;
  unsigned short* vpp = kph + PLANE;
  unsigned short* oh  = vpp + PLANE;

  dim3 gg(8, 64), bb(256);
  gemm_nt<true, false><<<gg, bb, 0, stream>>>(q, Wq, bq, qph);
  gemm_nt<true, false><<<gg, bb, 0, stream>>>(k, Wk, bk, kph);
  gemm_nt<true, false><<<gg, bb, 0, stream>>>(v, Wv, bv, vpp);

  dim3 ga(32, 64);
  attn_fused<<<ga, bb, 0, stream>>>(qph, kph, vpp, attn, oh);

  gemm_nt<false, true><<<gg, bb, 0, stream>>>(oh, Wo, bo, out);
}